// Round 1
// baseline (1065.869 us; speedup 1.0000x reference)
//
#include <hip/hip_runtime.h>

// ConvSV: per atom n
//   avf[a][g][d] = sum_m a[nbmat[n][m]][a] * g_sv[n][m][g][d]
//   out[n][0:256]   = avf[a][g][0]            (index a*16+g)
//   t[a][h][d=1..3] = sum_g agh[a][g][h] * avf[a][g][d]
//   out[n][256:512] = sum_d t^2               (index a*16+h)
//
// Memory-bound on the g_sv stream (819 MB). One wave per atom.

#define NATOMS 50000
#define MNB    64
#define WPB    4      // waves (atoms) per 256-thread block

__global__ __launch_bounds__(256) void convsv_kernel(
    const float* __restrict__ a,      // [N][16]
    const int*   __restrict__ nbmat,  // [N][64]
    const float* __restrict__ g_sv,   // [N][64][16][4]
    const float* __restrict__ agh,    // [16][16][16]
    float*       __restrict__ out)    // [N][512]
{
    // per-wave LDS region: [g][a][d] with g-stride 72 floats
    // (72*4=288 B keeps float4 reads 16B-aligned; %32 spread limits conflicts)
    __shared__ float Lds[WPB][16 * 72];

    const int tid  = threadIdx.x;
    const int lane = tid & 63;
    const int wave = tid >> 6;
    const int n    = blockIdx.x * WPB + wave;   // 12500*4 == 50000 exactly

    float* Lw = Lds[wave];

    // ---------------- stage 1: avf accumulation ----------------
    // lane <-> (g = lane>>2, d = lane&3); g_sv[n][m][*] flat offset = lane
    const int nb = nbmat[(size_t)n * MNB + lane];          // coalesced row load
    const float* gbase = g_sv + (size_t)n * (MNB * 64) + lane;

    float acc[16];
    #pragma unroll
    for (int c = 0; c < 16; ++c) acc[c] = 0.0f;

    #pragma unroll 4
    for (int m = 0; m < MNB; ++m) {
        const int idx = __builtin_amdgcn_readlane(nb, m);  // wave-uniform neighbor idx
        const float gv = gbase[(size_t)m * 64];            // 256B coalesced per wave
        const float* ar = a + (size_t)idx * 16;            // uniform address -> bcast
        #pragma unroll
        for (int c = 0; c < 16; ++c)
            acc[c] = fmaf(ar[c], gv, acc[c]);
    }

    // scatter acc to LDS: L[g*72 + a*4 + d]
    {
        const int gq = lane >> 2;
        const int dq = lane & 3;
        float* p = Lw + gq * 72 + dq;
        #pragma unroll
        for (int c = 0; c < 16; ++c)
            p[c * 4] = acc[c];
    }
    __syncthreads();

    // ---------------- stage 2: agh contraction + square-sum ----------------
    // lane <-> (a2 = lane&15, hb = lane>>4); handles h = hb*4 + k, k=0..3
    const int a2 = lane & 15;
    const int hb = lane >> 4;

    float t[4][3];
    #pragma unroll
    for (int k = 0; k < 4; ++k)
        #pragma unroll
        for (int d = 0; d < 3; ++d) t[k][d] = 0.0f;

    const float* aghp = agh + a2 * 256 + hb * 4;           // agh[a2][g][hb*4..+3]
    #pragma unroll
    for (int g = 0; g < 16; ++g) {
        const float4 av = *(const float4*)(Lw + g * 72 + a2 * 4);  // d=0..3
        const float4 ag = *(const float4*)(aghp + g * 16);         // k=0..3 (L1-resident)
        const float agk[4] = {ag.x, ag.y, ag.z, ag.w};
        const float avd[3] = {av.y, av.z, av.w};                   // d=1..3
        #pragma unroll
        for (int k = 0; k < 4; ++k)
            #pragma unroll
            for (int d = 0; d < 3; ++d)
                t[k][d] = fmaf(agk[k], avd[d], t[k][d]);
    }

    float* orow = out + (size_t)n * 512;

    // scalar part: out[p] = avf[p>>4][p&15][0], p in [0,256)
    #pragma unroll
    for (int j = 0; j < 4; ++j) {
        const int p = lane + 64 * j;
        orow[p] = Lw[(p & 15) * 72 + (p >> 4) * 4];        // coalesced 256B stores
    }

    // vector part: out[256 + a2*16 + hb*4 + k] = sum_d t[k][d]^2
    float4 ov;
    ov.x = fmaf(t[0][0], t[0][0], fmaf(t[0][1], t[0][1], t[0][2] * t[0][2]));
    ov.y = fmaf(t[1][0], t[1][0], fmaf(t[1][1], t[1][1], t[1][2] * t[1][2]));
    ov.z = fmaf(t[2][0], t[2][0], fmaf(t[2][1], t[2][1], t[2][2] * t[2][2]));
    ov.w = fmaf(t[3][0], t[3][0], fmaf(t[3][1], t[3][1], t[3][2] * t[3][2]));
    *(float4*)(orow + 256 + a2 * 16 + hb * 4) = ov;
}

extern "C" void kernel_launch(void* const* d_in, const int* in_sizes, int n_in,
                              void* d_out, int out_size, void* d_ws, size_t ws_size,
                              hipStream_t stream) {
    const float* a     = (const float*)d_in[0];
    const int*   nbmat = (const int*)  d_in[1];
    const float* g_sv  = (const float*)d_in[2];
    const float* agh   = (const float*)d_in[3];
    float*       out   = (float*)d_out;

    convsv_kernel<<<NATOMS / WPB, 256, 0, stream>>>(a, nbmat, g_sv, agh, out);
}